// Round 4
// baseline (614.308 us; speedup 1.0000x reference)
//
#include <hip/hip_runtime.h>

#define N_NODES  100000
#define N_EDGES  3200000
#define N_FEAT   512
#define N_GRAPHS 64
#define N_COLS   516
#define NBINS    1563               // ceil(N_NODES / 64), 64 nodes per bin
#define B1       256                // histogram column blocks
#define EPB      (N_EDGES / B1)     // 12500 edges per block chunk
#define CHUNK    20                 // rows per wave in the fused x pass
#define NWAVES   (N_NODES / CHUNK)  // 5000, exact
#define SRC_MASK 0x1FFFF

typedef float f4v __attribute__((ext_vector_type(4)));

// ---------------------------------------------------------------------------
// K1 prep: zero out[] + done counter, find graph starts, per-block edge hist.
// grid = B1 x 1024.
// ---------------------------------------------------------------------------
__global__ __launch_bounds__(1024) void prep_kernel(
    const int* __restrict__ edst, const int* __restrict__ gid,
    int* __restrict__ histG, int* __restrict__ starts,
    float* __restrict__ outz, int* __restrict__ done)
{
    __shared__ int lh[NBINS];
    const int b = blockIdx.x, tid = threadIdx.x;
    const int gtid = b * 1024 + tid;

    if (gtid == 0) *done = 0;
    if (gtid < N_GRAPHS * N_COLS) outz[gtid] = 0.f;
    if (gtid < N_NODES) {
        const int g = gid[gtid];
        const int gp = gtid ? gid[gtid - 1] : -1;
        for (int q = gp + 1; q <= g; ++q) starts[q] = gtid;
        if (gtid == N_NODES - 1)
            for (int q = g + 1; q <= N_GRAPHS; ++q) starts[q] = N_NODES;
    }
    for (int i = tid; i < NBINS; i += 1024) lh[i] = 0;
    __syncthreads();
    const int e0 = b * EPB;
    for (int e = e0 + tid; e < e0 + EPB; e += 1024)
        atomicAdd(&lh[edst[e] >> 6], 1);
    __syncthreads();
    for (int i = tid; i < NBINS; i += 1024) histG[i * B1 + b] = lh[i];
}

// ---------------------------------------------------------------------------
// K2 fused x pass: one NT read of x computes
//   p0[n]=x.Wn, s0[n]=x.Ws (wave-per-row, shuffle reduce)
//   per-graph colsum partials (registers -> per-wave slots; no atomics)
// Wave w owns rows [20w, 20w+20). Lane l owns cols [8l, 8l+8).
// ---------------------------------------------------------------------------
__device__ __forceinline__ void flush_cs(
    int si, int cur_g, const float a[8], int wave, int lane,
    float* __restrict__ pp, int* __restrict__ pt, float* __restrict__ out)
{
    if (si < 2) {
        const int slot = wave * 2 + si;
        if (lane == 0) pt[slot] = cur_g;
        float* d = pp + (size_t)slot * N_FEAT + lane * 8;
        *(float4*)d       = make_float4(a[0], a[1], a[2], a[3]);
        *(float4*)(d + 4) = make_float4(a[4], a[5], a[6], a[7]);
    } else {  // >2 graphs in one 20-row window: essentially impossible, but safe
        float* o = out + (size_t)cur_g * N_COLS + lane * 8;
        #pragma unroll
        for (int k = 0; k < 8; ++k) atomicAdd(o + k, a[k]);
    }
}

__global__ __launch_bounds__(256) void pass_x_kernel(
    const float* __restrict__ x, const int* __restrict__ gid,
    const float* __restrict__ wn, const float* __restrict__ ws,
    float* __restrict__ p0, float* __restrict__ s0,
    float* __restrict__ out, float* __restrict__ pp, int* __restrict__ pt)
{
    const int wave = (blockIdx.x * blockDim.x + threadIdx.x) >> 6;
    const int lane = threadIdx.x & 63;
    const int start = wave * CHUNK, end = start + CHUNK;   // exact fit

    const float4 wna = *(const float4*)(wn + lane * 8);
    const float4 wnb = *(const float4*)(wn + lane * 8 + 4);
    const float4 wsa = *(const float4*)(ws + lane * 8);
    const float4 wsb = *(const float4*)(ws + lane * 8 + 4);

    float a[8] = {0.f, 0.f, 0.f, 0.f, 0.f, 0.f, 0.f, 0.f};
    int cur_g = gid[start];
    const bool uniform = (gid[end - 1] == cur_g);
    int si = 0;

    for (int n = start; n < end; ++n) {
        if (!uniform) {
            const int g = gid[n];
            if (g != cur_g) {
                flush_cs(si, cur_g, a, wave, lane, pp, pt, out);
                ++si;
                #pragma unroll
                for (int k = 0; k < 8; ++k) a[k] = 0.f;
                cur_g = g;
            }
        }
        const float* row = x + (size_t)n * N_FEAT;
        const f4v xa = __builtin_nontemporal_load((const f4v*)(row + lane * 8));
        const f4v xb = __builtin_nontemporal_load((const f4v*)(row + lane * 8 + 4));

        a[0] += xa.x; a[1] += xa.y; a[2] += xa.z; a[3] += xa.w;
        a[4] += xb.x; a[5] += xb.y; a[6] += xb.z; a[7] += xb.w;

        float dn = xa.x*wna.x + xa.y*wna.y + xa.z*wna.z + xa.w*wna.w
                 + xb.x*wnb.x + xb.y*wnb.y + xb.z*wnb.z + xb.w*wnb.w;
        float dv = xa.x*wsa.x + xa.y*wsa.y + xa.z*wsa.z + xa.w*wsa.w
                 + xb.x*wsb.x + xb.y*wsb.y + xb.z*wsb.z + xb.w*wsb.w;
        #pragma unroll
        for (int off = 32; off > 0; off >>= 1) {
            dn += __shfl_down(dn, off);
            dv += __shfl_down(dv, off);
        }
        if (lane == 0) { p0[n] = dn; s0[n] = dv; }
    }
    flush_cs(si, cur_g, a, wave, lane, pp, pt, out);
    ++si;
    if (lane == 0)
        for (int s2 = si; s2 < 2; ++s2) pt[wave * 2 + s2] = -1;
}

// ---------------------------------------------------------------------------
// K3 fused scan: per-bin exclusive scan across B1 blocks; the LAST block to
// finish also scans the bin totals into binstart[NBINS+1].
// ---------------------------------------------------------------------------
__global__ __launch_bounds__(256) void scan_fused_kernel(
    const int* __restrict__ histG, int* __restrict__ colscanG,
    int* __restrict__ totalG, int* __restrict__ binstart, int* __restrict__ done)
{
    __shared__ int sc[256];
    __shared__ int lastflag;
    const int bin = blockIdx.x, t = threadIdx.x;
    const int v = histG[bin * B1 + t];
    sc[t] = v;
    __syncthreads();
    for (int off = 1; off < 256; off <<= 1) {
        const int a = (t >= off) ? sc[t - off] : 0;
        __syncthreads();
        sc[t] += a;
        __syncthreads();
    }
    colscanG[bin * B1 + t] = sc[t] - v;
    if (t == 255) totalG[bin] = sc[255];

    __threadfence();
    if (t == 0) lastflag = (atomicAdd(done, 1) == NBINS - 1);
    __syncthreads();
    if (!lastflag) return;
    __threadfence();

    // scan2: exclusive scan of totalG -> binstart
    const int CH = 7;                     // 256*7 >= NBINS
    int loc[CH];
    int s = 0;
    for (int i = 0; i < CH; ++i) {
        const int b2 = t * CH + i;
        const int vv = (b2 < NBINS) ? totalG[b2] : 0;
        loc[i] = s; s += vv;
    }
    const int my = s;
    __syncthreads();
    sc[t] = my;
    __syncthreads();
    for (int off = 1; off < 256; off <<= 1) {
        const int a = (t >= off) ? sc[t - off] : 0;
        __syncthreads();
        sc[t] += a;
        __syncthreads();
    }
    const int texcl = sc[t] - my;
    for (int i = 0; i < CH; ++i) {
        const int b2 = t * CH + i;
        if (b2 < NBINS) binstart[b2] = texcl + loc[i];
    }
    if (t == 255) binstart[NBINS] = sc[255];
}

// ---------------------------------------------------------------------------
// K4: blocks 0..B1-1 reorder edges into dst-bin order
//     (sorted[p] = src | (dst&63)<<17); blocks B1..B1+31 fold the colsum
//     partials into out (independent work, runs concurrently).
// ---------------------------------------------------------------------------
__global__ __launch_bounds__(1024) void reorder_reduce_kernel(
    const int* __restrict__ esrc, const int* __restrict__ edst,
    const int* __restrict__ binstart, const int* __restrict__ colscanG,
    int* __restrict__ sorted,
    const float* __restrict__ pp, const int* __restrict__ pt,
    const int* __restrict__ starts, float* __restrict__ out)
{
    const int b = blockIdx.x, tid = threadIdx.x;
    if (b < B1) {
        __shared__ int offs[NBINS];
        for (int i = tid; i < NBINS; i += 1024)
            offs[i] = binstart[i] + colscanG[i * B1 + b];
        __syncthreads();
        const int e0 = b * EPB;
        for (int e = e0 + tid; e < e0 + EPB; e += 1024) {
            const int s = esrc[e], d = edst[e];
            const int p = atomicAdd(&offs[d >> 6], 1);
            sorted[p] = s | ((d & 63) << 17);
        }
    } else {
        const int g = (b - B1) * 2 + (tid >> 9);   // 2 graphs per block
        const int c = tid & 511;
        const int s = starts[g], e = starts[g + 1];
        float acc = 0.f;
        if (e > s) {
            const int w0 = s / CHUNK, w1 = (e - 1) / CHUNK;
            for (int w = w0; w <= w1; ++w) {
                #pragma unroll
                for (int k = 0; k < 2; ++k) {
                    const int slot = w * 2 + k;
                    if (pt[slot] == g) acc += pp[(size_t)slot * N_FEAT + c];
                }
            }
        }
        out[(size_t)g * N_COLS + c] += acc;
    }
}

// ---------------------------------------------------------------------------
// K5..K8 per-layer: block per 64-node bin, LDS-accumulated neighbor sum +
// fused node update + per-graph reduction (~1 global atomic per block).
// ---------------------------------------------------------------------------
__global__ __launch_bounds__(256) void binned_scatter_kernel(
    const int* __restrict__ sorted, const int* __restrict__ binstart,
    const float* __restrict__ pin, const float* __restrict__ self_in,
    const float* __restrict__ wself_p, const float* __restrict__ bias_p,
    const float* __restrict__ wnext_p,
    float* __restrict__ h_out, float* __restrict__ p_next,
    const int* __restrict__ gid, float* __restrict__ out, int col)
{
    __shared__ float acc[4][64];
    const int b = blockIdx.x, tid = threadIdx.x;
    ((float*)acc)[tid] = 0.f;
    __syncthreads();

    const int st = binstart[b], en = binstart[b + 1];
    const int w = tid >> 6;
    for (int e = st + tid; e < en; e += 256) {
        const int v = sorted[e];
        atomicAdd(&acc[w][v >> 17], pin[v & SRC_MASK]);
    }
    __syncthreads();

    if (tid < 64) {
        const int n = b * 64 + tid;
        const bool valid = (n < N_NODES);
        float h = 0.f;
        int g = 0;
        if (valid) {
            const float nb = acc[0][tid] + acc[1][tid] + acc[2][tid] + acc[3][tid];
            const float sw = wself_p ? *wself_p : 1.0f;
            const float v = nb + *bias_p + sw * self_in[n];
            h = v > 0.f ? v : 0.f;
            h_out[n] = h;
            if (wnext_p) p_next[n] = h * (*wnext_p);
            g = gid[n];
        }
        const int g0 = __shfl(g, 0);
        if (__all(!valid || g == g0)) {
            float s = h;
            #pragma unroll
            for (int off = 32; off > 0; off >>= 1) s += __shfl_down(s, off);
            if (tid == 0) atomicAdd(&out[(size_t)g0 * N_COLS + col], s);
        } else if (valid) {
            atomicAdd(&out[(size_t)g * N_COLS + col], h);
        }
    }
}

extern "C" void kernel_launch(void* const* d_in, const int* in_sizes, int n_in,
                              void* d_out, int out_size, void* d_ws, size_t ws_size,
                              hipStream_t stream)
{
    (void)in_sizes; (void)n_in; (void)out_size; (void)ws_size;

    const float* x    = (const float*)d_in[0];
    const int*   esrc = (const int*)d_in[1];
    const int*   edst = (const int*)d_in[2];
    const int*   gid  = (const int*)d_in[3];
    const float* Wn0  = (const float*)d_in[4];
    const float* Ws0  = (const float*)d_in[5];
    const float* b0p  = (const float*)d_in[6];
    const float* Wnr  = (const float*)d_in[7];
    const float* Wsr  = (const float*)d_in[8];
    const float* brp  = (const float*)d_in[9];
    float* out = (float*)d_out;

    // workspace layout (16B-aligned first)
    float* pp    = (float*)d_ws;                         // NWAVES*2*512 floats
    float* bufP  = pp + (size_t)NWAVES * 2 * N_FEAT;
    float* bufP2 = bufP  + N_NODES;
    float* bufS  = bufP2 + N_NODES;
    float* bufH  = bufS  + N_NODES;
    int*   pt       = (int*)(bufH + N_NODES);            // NWAVES*2
    int*   starts   = pt + NWAVES * 2;                   // 65
    int*   binstart = starts + (N_GRAPHS + 1);           // NBINS+1
    int*   totalG   = binstart + NBINS + 1;              // NBINS
    int*   done     = totalG + NBINS;                    // 1
    int*   histG    = done + 1;                          // NBINS*B1
    int*   colscanG = histG + (size_t)NBINS * B1;        // NBINS*B1
    int*   sorted   = colscanG + (size_t)NBINS * B1;     // N_EDGES

    prep_kernel<<<B1, 1024, 0, stream>>>(edst, gid, histG, starts, out, done);
    pass_x_kernel<<<NWAVES / 4, 256, 0, stream>>>(
        x, gid, Wn0, Ws0, bufP, bufS, out, pp, pt);
    scan_fused_kernel<<<NBINS, 256, 0, stream>>>(
        histG, colscanG, totalG, binstart, done);
    reorder_reduce_kernel<<<B1 + N_GRAPHS / 2, 1024, 0, stream>>>(
        esrc, edst, binstart, colscanG, sorted, pp, pt, starts, out);

    binned_scatter_kernel<<<NBINS, 256, 0, stream>>>(
        sorted, binstart, bufP, bufS, nullptr, b0p, Wnr + 0, bufH, bufP2, gid, out, 512);
    binned_scatter_kernel<<<NBINS, 256, 0, stream>>>(
        sorted, binstart, bufP2, bufH, Wsr + 0, brp + 0, Wnr + 1, bufH, bufP, gid, out, 513);
    binned_scatter_kernel<<<NBINS, 256, 0, stream>>>(
        sorted, binstart, bufP, bufH, Wsr + 1, brp + 1, Wnr + 2, bufH, bufP2, gid, out, 514);
    binned_scatter_kernel<<<NBINS, 256, 0, stream>>>(
        sorted, binstart, bufP2, bufH, Wsr + 2, brp + 2, nullptr, bufH, nullptr, gid, out, 515);
}